// Round 7
// baseline (10304.920 us; speedup 1.0000x reference)
//
#include <hip/hip_runtime.h>
#include <hip/hip_cooperative_groups.h>
#include <cstdint>
#include <cstddef>

#define BB 32
#define NN 256
#define PP 3072
#define NG 192   // pixel groups of 16
#define RING 16

namespace cg = cooperative_groups;
typedef short v8us __attribute__((ext_vector_type(8)));

// One cooperative kernel runs the whole simulation.
// Blocks 0..191: spike role (group g = 16 pixels); phase 0 they compute
// x@W_init partials (6 K-chunks x 32 batches). Blocks 192..223: theta role
// (one batch each) — theta ring/gamma/a stay in LDS+registers throughout.
__global__ __launch_bounds__(512, 1) void k_mega(
    const float* __restrict__ x, const float* __restrict__ theta0,
    const float* __restrict__ W_init, const float* __restrict__ omega,
    const float* __restrict__ W_ro, const float* __restrict__ W_gate,
    const float* __restrict__ W_rec, const float* __restrict__ W_fb,
    const float* __restrict__ W_cls, const float* __restrict__ bcls,
    float* __restrict__ out, double* __restrict__ gateT,
    double* __restrict__ memD, float* __restrict__ rate,
    unsigned short* __restrict__ maskA, unsigned short* __restrict__ maskB,
    unsigned short* __restrict__ spk_list, int* __restrict__ spk_cnt,
    double* __restrict__ gpart) {
  cg::grid_group grid = cg::this_grid();
  __shared__ double smem[8192];  // 64 KB, role-dependent layout
  const int blk = blockIdx.x, tid = threadIdx.x;
  const bool is_theta = (blk >= NG);
  const int lane = tid & 63, wid = tid >> 6;
  const int j = tid & 255, half = tid >> 8;

  // theta-role LDS carve (45.2 KB of the 64)
  double* ring = smem;                                   // 16*256 dbl
  double* th = smem + 4096;                              // 256 dbl
  double* red = smem + 4352;                             // 32 dbl
  double* ahalf = smem + 4384;                           // 256 dbl
  int* pc = (int*)(smem + 4640);                         // 192 int
  int* sc = pc + NG;                                     // 192 int
  unsigned short* m_l = (unsigned short*)(sc + NG);      // 192 u16
  unsigned short* list_l = m_l + NG;                     // 3072 u16

  double t = 0.0, aj = 0.0, gm = 0.0, om = 0.0;  // theta per-thread state

  // ================= PHASE 0: init =================
  if (!is_theta) {
    // x@W_init partial: block = (batch b, K-chunk kc of 512)
    const int b = blk & 31, kc = blk >> 5;
    smem[tid] = (double)x[(size_t)b * PP + kc * 512 + tid];
    __syncthreads();
    const int osc = j, kh = half;  // osc 0..255, K-half 0/1
    const float* wp = W_init + (size_t)(kc * 512 + kh * 256) * NN + osc;
    const double* xp = smem + kh * 256;
    double a0 = 0, a1 = 0, a2 = 0, a3 = 0, a4 = 0, a5 = 0, a6 = 0, a7 = 0;
    for (int p = 0; p < 256; p += 8) {
      a0 += xp[p + 0] * (double)wp[(size_t)(p + 0) * NN];
      a1 += xp[p + 1] * (double)wp[(size_t)(p + 1) * NN];
      a2 += xp[p + 2] * (double)wp[(size_t)(p + 2) * NN];
      a3 += xp[p + 3] * (double)wp[(size_t)(p + 3) * NN];
      a4 += xp[p + 4] * (double)wp[(size_t)(p + 4) * NN];
      a5 += xp[p + 5] * (double)wp[(size_t)(p + 5) * NN];
      a6 += xp[p + 6] * (double)wp[(size_t)(p + 6) * NN];
      a7 += xp[p + 7] * (double)wp[(size_t)(p + 7) * NN];
    }
    double acc = ((a0 + a1) + (a2 + a3)) + ((a4 + a5) + (a6 + a7));
    __syncthreads();
    if (kh) smem[osc] = acc;
    __syncthreads();
    if (!kh) gpart[((size_t)kc * 32 + b) * 256 + osc] = acc + smem[osc];
  } else {
    const int b = blk - NG;
    for (int i = tid; i < PP; i += 512) {
      memD[(size_t)b * PP + i] = 0.0;
      rate[(size_t)b * PP + i] = 0.f;
    }
    for (int i = tid; i < NG; i += 512) {
      maskA[b * NG + i] = 0;
      maskB[b * NG + i] = 0;
    }
    if (tid == 0) spk_cnt[b] = 0;
    if (tid < 256) {
      t = (double)theta0[b * NN + j];
      om = (double)omega[j];
    }
  }
  __threadfence();
  grid.sync();

  // ================= main loop: 40 groups of 5 steps =================
  for (int k2 = 0; k2 <= 39; ++k2) {
    if (k2 > 0) {
      // ---------- SPIKE phase (s = 5*k2+1) ----------
      if (!is_theta) {
        const int g = blk, j0 = g * 16;
        for (int i = tid; i < NN * BB; i += 512) smem[i] = gateT[i];
        __syncthreads();
        const int pi = tid & 15, b = tid >> 4, p = j0 + pi;
        const unsigned short* mrd = (k2 & 1) ? maskA : maskB;
        unsigned short* mwr = (k2 & 1) ? maskB : maskA;
        const int cnt = spk_cnt[b];
        // gate dot: K=256 fp64, gate from LDS, W_gate from L2
        double g0 = 0, g1 = 0, g2 = 0, g3 = 0;
        for (int k = 0; k < NN; k += 4) {
          g0 += smem[(k + 0) * BB + b] * (double)W_gate[(size_t)(k + 0) * PP + p];
          g1 += smem[(k + 1) * BB + b] * (double)W_gate[(size_t)(k + 1) * PP + p];
          g2 += smem[(k + 2) * BB + b] * (double)W_gate[(size_t)(k + 2) * PP + p];
          g3 += smem[(k + 3) * BB + b] * (double)W_gate[(size_t)(k + 3) * PP + p];
        }
        const double vg = (g0 + g1) + (g2 + g3);
        // rec: compact active-pixel list, 8 independent streams
        double v0 = 0, v1 = 0, v2 = 0, v3 = 0, v4 = 0, v5 = 0, v6 = 0, v7 = 0;
        const unsigned short* lst = spk_list + (size_t)b * PP;
        int i = 0;
        for (; i + 8 <= cnt; i += 8) {
          v8us r = *reinterpret_cast<const v8us*>(lst + i);
          v0 += (double)W_rec[(size_t)(unsigned short)r[0] * PP + p];
          v1 += (double)W_rec[(size_t)(unsigned short)r[1] * PP + p];
          v2 += (double)W_rec[(size_t)(unsigned short)r[2] * PP + p];
          v3 += (double)W_rec[(size_t)(unsigned short)r[3] * PP + p];
          v4 += (double)W_rec[(size_t)(unsigned short)r[4] * PP + p];
          v5 += (double)W_rec[(size_t)(unsigned short)r[5] * PP + p];
          v6 += (double)W_rec[(size_t)(unsigned short)r[6] * PP + p];
          v7 += (double)W_rec[(size_t)(unsigned short)r[7] * PP + p];
        }
        double vr = ((v0 + v1) + (v2 + v3)) + ((v4 + v5) + (v6 + v7));
        for (; i < cnt; ++i) vr += (double)W_rec[(size_t)lst[i] * PP + p];

        const double cur = vg + 0.1 * vr;
        const double so = (double)((mrd[b * NG + g] >> pi) & 1);
        const size_t idx = (size_t)b * PP + p;
        const double mv = 0.9 * memD[idx] * (1.0 - so) + cur;
        const double sv = (mv - 1.0 > 0.0) ? 1.0 : 0.0;
        memD[idx] = mv;
        if (k2 >= 10) rate[idx] += (float)sv;
        unsigned long long bal = __ballot(sv > 0.5);
        const int bl = lane >> 4, wb = (tid >> 6) * 4;
        if ((lane & 15) == 0)
          mwr[(wb + bl) * NG + g] =
              (unsigned short)((bal >> (16 * bl)) & 0xFFFFull);
      }
      __threadfence();
      grid.sync();
    }

    // ---------- THETA phase: steps 5*k2+1 .. 5*k2+5 ----------
    if (is_theta) {
      const int b = blk - NG;
      double new_a = 0.0;
      int total = 0;
      if (k2 > 0) {
        // compact the fresh spike mask into a sorted pixel list
        const unsigned short* mc = (k2 & 1) ? maskB : maskA;
        if (tid < NG) {
          m_l[tid] = mc[b * NG + tid];
          pc[tid] = __popc((unsigned int)m_l[tid]);
          sc[tid] = pc[tid];
        }
        __syncthreads();
        for (int d = 1; d < NG; d <<= 1) {
          int v = 0;
          if (tid < NG) v = sc[tid] + ((tid >= d) ? sc[tid - d] : 0);
          __syncthreads();
          if (tid < NG) sc[tid] = v;
          __syncthreads();
        }
        total = sc[NG - 1];
        if (tid < NG) {
          int off = sc[tid] - pc[tid];
          unsigned int m = m_l[tid];
          while (m) {
            int bit = __builtin_ctz(m);
            m &= m - 1;
            list_l[off++] = (unsigned short)(tid * 16 + bit);
          }
        }
        __syncthreads();
        for (int i = tid; i < total; i += 512)
          spk_list[(size_t)b * PP + i] = list_l[i];
        if (tid == 0) spk_cnt[b] = total;
        // a = tanh(spk @ W_fb): 8 streams over the compact list
        double c0 = 0, c1 = 0, c2 = 0, c3 = 0, c4 = 0, c5 = 0, c6 = 0, c7 = 0;
        int i = half;
        for (; i + 16 <= total; i += 16) {
          c0 += (double)W_fb[(size_t)list_l[i + 0] * NN + j];
          c1 += (double)W_fb[(size_t)list_l[i + 2] * NN + j];
          c2 += (double)W_fb[(size_t)list_l[i + 4] * NN + j];
          c3 += (double)W_fb[(size_t)list_l[i + 6] * NN + j];
          c4 += (double)W_fb[(size_t)list_l[i + 8] * NN + j];
          c5 += (double)W_fb[(size_t)list_l[i + 10] * NN + j];
          c6 += (double)W_fb[(size_t)list_l[i + 12] * NN + j];
          c7 += (double)W_fb[(size_t)list_l[i + 14] * NN + j];
        }
        double acc = ((c0 + c1) + (c2 + c3)) + ((c4 + c5) + (c6 + c7));
        for (; i < total; i += 2) acc += (double)W_fb[(size_t)list_l[i] * NN + j];
        if (half) ahalf[j] = acc;
        __syncthreads();
        if (!half) new_a = tanh(acc + ahalf[j]);
      } else {
        // gamma0 = tanh(x @ W_init) from phase-0 partials; seed the ring
        if (tid < 256) {
          double s = 0.0;
          for (int kc = 0; kc < 6; ++kc)
            s += gpart[((size_t)kc * 32 + b) * 256 + j];
          gm = tanh(s);
          ring[0 * NN + j] = t;
        }
        __syncthreads();
      }

      const int s0 = 5 * k2 + 1, s1 = 5 * k2 + 5;
      for (int s = s0; s <= s1; ++s) {
        if (tid < 256 && k2 > 0 && s == s0 + 1) aj = new_a;  // step s0 uses OLD a
        double sn = 0.0, cs = 0.0;
        if (tid < 256) sincos(t, &sn, &cs);
        double r0 = sn, r1 = cs, r2 = aj * sn, r3 = aj * cs;
#pragma unroll
        for (int o = 32; o; o >>= 1) {
          r0 += __shfl_down(r0, o);
          r1 += __shfl_down(r1, o);
          r2 += __shfl_down(r2, o);
          r3 += __shfl_down(r3, o);
        }
        if (lane == 0) {
          red[wid * 4 + 0] = r0;
          red[wid * 4 + 1] = r1;
          red[wid * 4 + 2] = r2;
          red[wid * 4 + 3] = r3;
        }
        __syncthreads();
        double S = red[0] + red[4] + red[8] + red[12];
        double C = red[1] + red[5] + red[9] + red[13];
        double AS = red[2] + red[6] + red[10] + red[14];
        double AC = red[3] + red[7] + red[11] + red[15];
        __syncthreads();
        if (tid < 256) {
          double base = cs * S - sn * C;
          double wgt = 0.5 * (cs * aj * AS - sn * aj * AC);
          t = t + 0.1 * (om + (1.0 / 256.0) * (base + wgt) + 0.5 * gm);
          ring[(s & (RING - 1)) * NN + j] = t;
        }
      }
      if (tid < 256) th[j] = t;
      __syncthreads();
      if (tid < 256) {
        // gamma = tanh(theta @ W_ro), 8 streams; then the sinusoidal gate
        double c0 = 0, c1 = 0, c2 = 0, c3 = 0, c4 = 0, c5 = 0, c6 = 0, c7 = 0;
        const float* wp = W_ro + j;
        for (int i = 0; i < NN; i += 8) {
          c0 += th[i + 0] * (double)wp[(size_t)(i + 0) * NN];
          c1 += th[i + 1] * (double)wp[(size_t)(i + 1) * NN];
          c2 += th[i + 2] * (double)wp[(size_t)(i + 2) * NN];
          c3 += th[i + 3] * (double)wp[(size_t)(i + 3) * NN];
          c4 += th[i + 4] * (double)wp[(size_t)(i + 4) * NN];
          c5 += th[i + 5] * (double)wp[(size_t)(i + 5) * NN];
          c6 += th[i + 6] * (double)wp[(size_t)(i + 6) * NN];
          c7 += th[i + 7] * (double)wp[(size_t)(i + 7) * NN];
        }
        gm = tanh(((c0 + c1) + (c2 + c3)) + ((c4 + c5) + (c6 + c7)));
        int sd = s1 - 11;
        if (sd < 0) sd = 0;
        double dly = ring[(sd & (RING - 1)) * NN + j];
        double gt = gm * 0.5 * (1.0 + cos(t - dly));
        gateT[j * BB + b] = gt;  // [osc][batch]
      }
      __syncthreads();
    }
    __threadfence();
    grid.sync();
  }

  // ================= classifier =================
  if (blk < BB) {
    const int b = blk;
    double acc[10];
#pragma unroll
    for (int c = 0; c < 10; ++c) acc[c] = 0.0;
    for (int p = tid; p < PP; p += 512) {
      double r = (double)rate[(size_t)b * PP + p] / 30.0;
#pragma unroll
      for (int c = 0; c < 10; ++c) acc[c] += r * (double)W_cls[(size_t)p * 10 + c];
    }
    double* sh = smem;  // 10 x 512 doubles = 40 KB
#pragma unroll
    for (int c = 0; c < 10; ++c) sh[c * 512 + tid] = acc[c];
    __syncthreads();
    for (int off = 256; off; off >>= 1) {
      if (tid < off)
#pragma unroll
        for (int c = 0; c < 10; ++c) sh[c * 512 + tid] += sh[c * 512 + tid + off];
      __syncthreads();
    }
    if (tid < 10) out[b * 10 + tid] = (float)(sh[tid * 512] + (double)bcls[tid]);
  }
}

extern "C" void kernel_launch(void* const* d_in, const int* in_sizes, int n_in,
                              void* d_out, int out_size, void* d_ws,
                              size_t ws_size, hipStream_t stream) {
  const float* x = (const float*)d_in[0];
  const float* theta0 = (const float*)d_in[1];
  const float* W_init = (const float*)d_in[2];
  const float* omega = (const float*)d_in[3];
  const float* W_ro = (const float*)d_in[4];
  const float* W_gate = (const float*)d_in[5];
  const float* W_rec = (const float*)d_in[6];
  const float* W_fb = (const float*)d_in[7];
  const float* W_cls = (const float*)d_in[8];
  const float* b_cls = (const float*)d_in[9];
  float* outp = (float*)d_out;

  char* w = (char*)d_ws;
  size_t off = 0;
  auto alloc = [&](size_t sz) -> void* {
    void* p = w + off;
    off = (off + sz + 255) & ~(size_t)255;
    return p;
  };
  double* gateT = (double*)alloc((size_t)BB * NN * 8);
  double* memD = (double*)alloc((size_t)BB * PP * 8);
  float* rate = (float*)alloc((size_t)BB * PP * 4);
  unsigned short* maskA = (unsigned short*)alloc((size_t)BB * NG * 2);
  unsigned short* maskB = (unsigned short*)alloc((size_t)BB * NG * 2);
  unsigned short* spk_list = (unsigned short*)alloc((size_t)BB * PP * 2);
  int* spk_cnt = (int*)alloc((size_t)BB * 4);
  double* gpart = (double*)alloc((size_t)6 * BB * NN * 8);
  // ~1.9 MB of ws

  void* args[] = {&x, &theta0, &W_init, &omega, &W_ro, &W_gate, &W_rec,
                  &W_fb, &W_cls, &b_cls, &outp, &gateT, &memD, &rate,
                  &maskA, &maskB, &spk_list, &spk_cnt, &gpart};
  hipLaunchCooperativeKernel((void*)k_mega, dim3(224), dim3(512), args, 0,
                             stream);
}